// Round 1
// baseline (719.960 us; speedup 1.0000x reference)
//
#include <hip/hip_runtime.h>

#define H 512
#define W 512
#define NIMG 128
#define TH 16
#define TW 128
#define XR (TH + 6)        // 22 staged rows
#define XC (TW + 6)        // 134 staged cols
#define XSTRIDE 136        // pad to keep float2 alignment / banks happy

#define YHR_OFF ((long)NIMG * H * W)                      // 33554432
#define BSTRIDE ((long)(H / 2) * (W / 2))                 // 65536
#define YH_SIZE ((long)NIMG * 6 * BSTRIDE)                // 50331648
#define YHI_OFF (YHR_OFF + YH_SIZE)                       // 83886080

__device__ __forceinline__ int reflect512(int g) {
    // symmetric (edge-inclusive) reflection, single fold is enough for |halo|<=3
    g = (g < 0) ? (-1 - g) : g;
    g = (g > H - 1) ? (2 * H - 1 - g) : g;
    return g;
}

__global__ __launch_bounds__(256, 4)
void dtcwt_fwd1(const float* __restrict__ x,
                const float* __restrict__ h0o,
                const float* __restrict__ h1o,
                float* __restrict__ out)
{
    __shared__ float xin[XR][XSTRIDE];
    __shared__ float slo[XR][TW];
    __shared__ float shi[XR][TW];

    const int tid = threadIdx.x;
    const int x0 = blockIdx.x * TW;
    const int y0 = blockIdx.y * TH;
    const int img = blockIdx.z;

    // taps: uniform address -> compiler emits s_load; 5-tap h0o (p=2), 7-tap h1o (p=3)
    float c0[5], c1[7];
#pragma unroll
    for (int j = 0; j < 5; ++j) c0[j] = h0o[j];
#pragma unroll
    for (int j = 0; j < 7; ++j) c1[j] = h1o[j];

    const long ibase = (long)img * (H * W);

    // ---- Phase 1: global -> LDS input tile with symmetric halo (3 each side) ----
    for (int i = tid; i < XR * XC; i += 256) {
        int r = i / XC;
        int c = i - r * XC;
        int gy = reflect512(y0 - 3 + r);
        int gx = reflect512(x0 - 3 + c);
        xin[r][c] = x[ibase + gy * W + gx];
    }
    __syncthreads();

    // ---- Phase 2: row filters (cross-correlation) -> slo/shi ----
    // output local col w corresponds to abs x0+w; xin local col lc = abs - (x0-3)
    // Lo[w] = sum_j h0[j]*xin[r][w+1+j]; Hi[w] = sum_j h1[j]*xin[r][w+j]
    for (int i = tid; i < XR * (TW / 2); i += 256) {
        int r = i >> 6;               // TW/2 == 64
        int wp = (i & 63) * 2;
        float2 a0 = *(const float2*)&xin[r][wp];
        float2 a1 = *(const float2*)&xin[r][wp + 2];
        float2 a2 = *(const float2*)&xin[r][wp + 4];
        float2 a3 = *(const float2*)&xin[r][wp + 6];
        float w0v = a0.x, w1v = a0.y, w2v = a1.x, w3v = a1.y;
        float w4v = a2.x, w5v = a2.y, w6v = a3.x, w7v = a3.y;
        float lo0 = c0[0]*w1v + c0[1]*w2v + c0[2]*w3v + c0[3]*w4v + c0[4]*w5v;
        float lo1 = c0[0]*w2v + c0[1]*w3v + c0[2]*w4v + c0[3]*w5v + c0[4]*w6v;
        float hi0 = c1[0]*w0v + c1[1]*w1v + c1[2]*w2v + c1[3]*w3v + c1[4]*w4v
                  + c1[5]*w5v + c1[6]*w6v;
        float hi1 = c1[0]*w1v + c1[1]*w2v + c1[2]*w3v + c1[3]*w4v + c1[4]*w5v
                  + c1[5]*w6v + c1[6]*w7v;
        *(float2*)&slo[r][wp] = make_float2(lo0, lo1);
        *(float2*)&shi[r][wp] = make_float2(hi0, hi1);
    }
    __syncthreads();

    // ---- Phase 3: column filters + q2c per 2x2 quad ----
    // output local row rr: LoLo = sum_j h0[j]*slo[rr+1+j][w], LoHi = sum_j h1[j]*slo[rr+j][w]
    const float s = 0.70710678118654752440f;
    for (int i = tid; i < (TH / 2) * (TW / 2); i += 256) {
        int qr = i >> 6;              // 0..7
        int qw = i & 63;              // 0..63
        int r0 = qr * 2;              // top pixel local row
        int w0 = qw * 2;              // left pixel local col
        float2 L[8], Hv[8];
#pragma unroll
        for (int j = 0; j < 8; ++j) {
            L[j]  = *(const float2*)&slo[r0 + j][w0];
            Hv[j] = *(const float2*)&shi[r0 + j][w0];
        }
        float ll00 = 0.f, ll01 = 0.f, ll10 = 0.f, ll11 = 0.f;
        float hl_a = 0.f, hl_b = 0.f, hl_c = 0.f, hl_d = 0.f;
#pragma unroll
        for (int j = 0; j < 5; ++j) {
            ll00 += c0[j] * L[1 + j].x;  ll01 += c0[j] * L[1 + j].y;
            ll10 += c0[j] * L[2 + j].x;  ll11 += c0[j] * L[2 + j].y;
            hl_a += c0[j] * Hv[1 + j].x; hl_b += c0[j] * Hv[1 + j].y;
            hl_c += c0[j] * Hv[2 + j].x; hl_d += c0[j] * Hv[2 + j].y;
        }
        float lh_a = 0.f, lh_b = 0.f, lh_c = 0.f, lh_d = 0.f;
        float hh_a = 0.f, hh_b = 0.f, hh_c = 0.f, hh_d = 0.f;
#pragma unroll
        for (int j = 0; j < 7; ++j) {
            lh_a += c1[j] * L[j].x;      lh_b += c1[j] * L[j].y;
            lh_c += c1[j] * L[1 + j].x;  lh_d += c1[j] * L[1 + j].y;
            hh_a += c1[j] * Hv[j].x;     hh_b += c1[j] * Hv[j].y;
            hh_c += c1[j] * Hv[1 + j].x; hh_d += c1[j] * Hv[1 + j].y;
        }

        // Yl = LoLo, full resolution
        long ylb = ibase + (long)(y0 + r0) * W + (x0 + w0);
        *(float2*)&out[ylb]     = make_float2(ll00, ll01);
        *(float2*)&out[ylb + W] = make_float2(ll10, ll11);

        // q2c: a=(0,0) b=(0,1) c=(1,0) d=(1,1); z1=(a-d, b+c), z2=(a+d, b-c)
        // bands: 0=LoHi.z1 1=HiHi.z1 2=HiLo.z1 3=HiLo.z2 4=HiHi.z2 5=LoHi.z2
        int qy = (y0 >> 1) + qr;
        int qx = (x0 >> 1) + qw;
        long hb = (long)img * 6 * BSTRIDE + (long)qy * (W / 2) + qx;
        float* __restrict__ yhr = out + YHR_OFF;
        float* __restrict__ yhi = out + YHI_OFF;
        yhr[hb + 0 * BSTRIDE] = (lh_a - lh_d) * s;
        yhi[hb + 0 * BSTRIDE] = (lh_b + lh_c) * s;
        yhr[hb + 1 * BSTRIDE] = (hh_a - hh_d) * s;
        yhi[hb + 1 * BSTRIDE] = (hh_b + hh_c) * s;
        yhr[hb + 2 * BSTRIDE] = (hl_a - hl_d) * s;
        yhi[hb + 2 * BSTRIDE] = (hl_b + hl_c) * s;
        yhr[hb + 3 * BSTRIDE] = (hl_a + hl_d) * s;
        yhi[hb + 3 * BSTRIDE] = (hl_b - hl_c) * s;
        yhr[hb + 4 * BSTRIDE] = (hh_a + hh_d) * s;
        yhi[hb + 4 * BSTRIDE] = (hh_b - hh_c) * s;
        yhr[hb + 5 * BSTRIDE] = (lh_a + lh_d) * s;
        yhi[hb + 5 * BSTRIDE] = (lh_b - lh_c) * s;
    }
}

extern "C" void kernel_launch(void* const* d_in, const int* in_sizes, int n_in,
                              void* d_out, int out_size, void* d_ws, size_t ws_size,
                              hipStream_t stream) {
    const float* x   = (const float*)d_in[0];
    const float* h0o = (const float*)d_in[1];
    const float* h1o = (const float*)d_in[2];
    float* out = (float*)d_out;
    dim3 grid(W / TW, H / TH, NIMG);   // 4 x 32 x 128
    dtcwt_fwd1<<<grid, dim3(256), 0, stream>>>(x, h0o, h1o, out);
}